// Round 1
// baseline (3365.067 us; speedup 1.0000x reference)
//
#include <hip/hip_runtime.h>

#define N_USERS 100000
#define N_ITEMS 200000
#define N_NODES 300000
#define DIM 64

// One wave (64 lanes) per edge; lane = dim. Gather src[col][lane], scale by
// val, atomicAdd into dst[row][lane]. srcI == nullptr means src is a single
// contiguous [N,D] matrix (hop 2); otherwise src is the virtual concat
// [userE; itemE] (hop 1).
__global__ __launch_bounds__(256) void spmm_scatter(
    const int* __restrict__ rows, const int* __restrict__ cols,
    const float* __restrict__ vals, const float* __restrict__ srcU,
    const float* __restrict__ srcI, float* __restrict__ dst,
    float scale, int nEdges)
{
    const int lane = threadIdx.x & 63;
    const int wavesPerBlock = blockDim.x >> 6;
    long wave = (long)blockIdx.x * wavesPerBlock + (threadIdx.x >> 6);
    const long nWaves = (long)gridDim.x * wavesPerBlock;
    for (long e = wave; e < nEdges; e += nWaves) {
        const int r = rows[e];
        const int c = cols[e];
        const float v = vals[e] * scale;
        const float* src;
        if (srcI != nullptr) {
            src = (c < N_USERS) ? (srcU + (size_t)c * DIM)
                                : (srcI + (size_t)(c - N_USERS) * DIM);
        } else {
            src = srcU + (size_t)c * DIM;
        }
        atomicAdd(dst + (size_t)r * DIM + lane, v * src[lane]);
    }
}

// d_out = (emb + cur1) / 3, float4-vectorized. emb is virtual concat.
__global__ __launch_bounds__(256) void finalize_base(
    const float* __restrict__ userE, const float* __restrict__ itemE,
    const float* __restrict__ cur1, float* __restrict__ out)
{
    const long total4 = (long)N_NODES * DIM / 4;   // 4.8M float4
    const long user4  = (long)N_USERS * DIM / 4;   // 1.6M float4
    const float inv3 = 1.0f / 3.0f;
    for (long i = (long)blockIdx.x * blockDim.x + threadIdx.x; i < total4;
         i += (long)gridDim.x * blockDim.x) {
        float4 e = (i < user4) ? ((const float4*)userE)[i]
                               : ((const float4*)itemE)[i - user4];
        float4 c = ((const float4*)cur1)[i];
        float4 o;
        o.x = (e.x + c.x) * inv3;
        o.y = (e.y + c.y) * inv3;
        o.z = (e.z + c.z) * inv3;
        o.w = (e.w + c.w) * inv3;
        ((float4*)out)[i] = o;
    }
}

extern "C" void kernel_launch(void* const* d_in, const int* in_sizes, int n_in,
                              void* d_out, int out_size, void* d_ws, size_t ws_size,
                              hipStream_t stream)
{
    const int*   rows  = (const int*)d_in[0];
    const int*   cols  = (const int*)d_in[1];
    const float* vals  = (const float*)d_in[2];
    const float* userE = (const float*)d_in[3];
    const float* itemE = (const float*)d_in[4];
    float* out  = (float*)d_out;
    float* cur1 = (float*)d_ws;          // 300000*64*4 = 76.8 MB scratch
    const int nEdges = in_sizes[0];
    const size_t nodeBytes = (size_t)N_NODES * DIM * sizeof(float);

    // zero hop-1 accumulator (ws is poisoned, and not re-poisoned between replays)
    hipMemsetAsync(cur1, 0, nodeBytes, stream);

    dim3 blk(256);
    // hop 1: cur1 = A @ emb
    spmm_scatter<<<dim3(4096), blk, 0, stream>>>(rows, cols, vals, userE, itemE,
                                                 cur1, 1.0f, nEdges);
    // out = (emb + cur1)/3
    finalize_base<<<dim3(2048), blk, 0, stream>>>(userE, itemE, cur1, out);
    // hop 2: out += (A @ cur1)/3
    spmm_scatter<<<dim3(4096), blk, 0, stream>>>(rows, cols, vals, cur1, nullptr,
                                                 out, 1.0f / 3.0f, nEdges);
}

// Round 2
// 1405.723 us; speedup vs baseline: 2.3938x; 2.3938x over previous
//
#include <hip/hip_runtime.h>

#define DIM 64

__device__ __forceinline__ float i2f(int x) { union { int i; float f; } u; u.i = x; return u.f; }

// ---------------- CSR-build pipeline ----------------

__global__ __launch_bounds__(256) void k_hist(const int* __restrict__ rows,
                                              int* __restrict__ counts, int nE) {
    int i = blockIdx.x * blockDim.x + threadIdx.x;
    if (i < nE) atomicAdd(&counts[rows[i]], 1);
}

// per-block exclusive scan of counts -> excl, block totals -> blockSums
__global__ __launch_bounds__(1024) void k_scan1(const int* __restrict__ counts,
                                                int* __restrict__ excl,
                                                int* __restrict__ blockSums, int n) {
    __shared__ int s[1024];
    int i = blockIdx.x * 1024 + threadIdx.x;
    int v = (i < n) ? counts[i] : 0;
    s[threadIdx.x] = v; __syncthreads();
    for (int off = 1; off < 1024; off <<= 1) {
        int t = (threadIdx.x >= (unsigned)off) ? s[threadIdx.x - off] : 0;
        __syncthreads();
        s[threadIdx.x] += t;
        __syncthreads();
    }
    if (i < n) excl[i] = s[threadIdx.x] - v;
    if (threadIdx.x == 1023) blockSums[blockIdx.x] = s[1023];
}

// single-block scan of block sums (nB <= 512); also writes rowStart[n] = nE
__global__ __launch_bounds__(512) void k_scan2(const int* __restrict__ blockSums,
                                               int* __restrict__ blockOffs, int nB,
                                               int* __restrict__ rowStartEnd, int total) {
    __shared__ int s[512];
    int v = ((int)threadIdx.x < nB) ? blockSums[threadIdx.x] : 0;
    s[threadIdx.x] = v; __syncthreads();
    for (int off = 1; off < 512; off <<= 1) {
        int t = (threadIdx.x >= (unsigned)off) ? s[threadIdx.x - off] : 0;
        __syncthreads();
        s[threadIdx.x] += t;
        __syncthreads();
    }
    if ((int)threadIdx.x < nB) blockOffs[threadIdx.x] = s[threadIdx.x] - v;
    if (threadIdx.x == 0) *rowStartEnd = total;
}

__global__ __launch_bounds__(1024) void k_scan3(int* __restrict__ excl,
                                                const int* __restrict__ blockOffs, int n) {
    int i = blockIdx.x * 1024 + threadIdx.x;
    if (i < n) excl[i] += blockOffs[blockIdx.x];
}

__global__ __launch_bounds__(256) void k_scatter(const int* __restrict__ rows,
                                                 const int* __restrict__ cols,
                                                 const float* __restrict__ vals,
                                                 int* __restrict__ cursor,
                                                 int2* __restrict__ pairs, int nE) {
    int i = blockIdx.x * blockDim.x + threadIdx.x;
    if (i < nE) {
        int r = rows[i];
        int pos = atomicAdd(&cursor[r], 1);
        pairs[pos] = make_int2(cols[i], __float_as_int(vals[i]));
    }
}

// ---------------- CSR SpMM: one wave per row, lane = dim ----------------

// hop 1: cur1[r] = sum val * concat(uE,iE)[col]
__global__ __launch_bounds__(256) void k_spmm1(const int* __restrict__ rowStart,
                                               const int2* __restrict__ pairs,
                                               const float* __restrict__ uE,
                                               const float* __restrict__ iE,
                                               float* __restrict__ cur1,
                                               int nNodes, int nUsers) {
    const int lane = threadIdx.x & 63;
    int r = blockIdx.x * (blockDim.x >> 6) + (threadIdx.x >> 6);
    if (r >= nNodes) return;
    int start = __builtin_amdgcn_readfirstlane(rowStart[r]);
    int end   = __builtin_amdgcn_readfirstlane(rowStart[r + 1]);
    float acc = 0.f;
    int e = start;
    for (; e + 1 < end; e += 2) {
        int2 p0 = pairs[e], p1 = pairs[e + 1];
        const float* s0 = (p0.x < nUsers) ? uE + (size_t)p0.x * DIM
                                          : iE + (size_t)(p0.x - nUsers) * DIM;
        const float* s1 = (p1.x < nUsers) ? uE + (size_t)p1.x * DIM
                                          : iE + (size_t)(p1.x - nUsers) * DIM;
        float x0 = s0[lane], x1 = s1[lane];
        acc = fmaf(i2f(p0.y), x0, acc);
        acc = fmaf(i2f(p1.y), x1, acc);
    }
    if (e < end) {
        int2 p = pairs[e];
        const float* s = (p.x < nUsers) ? uE + (size_t)p.x * DIM
                                        : iE + (size_t)(p.x - nUsers) * DIM;
        acc = fmaf(i2f(p.y), s[lane], acc);
    }
    cur1[(size_t)r * DIM + lane] = acc;
}

// hop 2 fused epilogue: out[r] = (emb[r] + cur1[r] + sum val*cur1[col]) / 3
__global__ __launch_bounds__(256) void k_spmm2(const int* __restrict__ rowStart,
                                               const int2* __restrict__ pairs,
                                               const float* __restrict__ cur1,
                                               const float* __restrict__ uE,
                                               const float* __restrict__ iE,
                                               float* __restrict__ out,
                                               int nNodes, int nUsers) {
    const int lane = threadIdx.x & 63;
    int r = blockIdx.x * (blockDim.x >> 6) + (threadIdx.x >> 6);
    if (r >= nNodes) return;
    int start = __builtin_amdgcn_readfirstlane(rowStart[r]);
    int end   = __builtin_amdgcn_readfirstlane(rowStart[r + 1]);
    float acc = 0.f;
    int e = start;
    for (; e + 1 < end; e += 2) {
        int2 p0 = pairs[e], p1 = pairs[e + 1];
        float x0 = cur1[(size_t)p0.x * DIM + lane];
        float x1 = cur1[(size_t)p1.x * DIM + lane];
        acc = fmaf(i2f(p0.y), x0, acc);
        acc = fmaf(i2f(p1.y), x1, acc);
    }
    if (e < end) {
        int2 p = pairs[e];
        acc = fmaf(i2f(p.y), cur1[(size_t)p.x * DIM + lane], acc);
    }
    float em = (r < nUsers) ? uE[(size_t)r * DIM + lane]
                            : iE[(size_t)(r - nUsers) * DIM + lane];
    out[(size_t)r * DIM + lane] = (em + cur1[(size_t)r * DIM + lane] + acc) * (1.0f / 3.0f);
}

// ---------------- fallback (round-1 atomic path) ----------------

__global__ __launch_bounds__(256) void spmm_scatter(
    const int* __restrict__ rows, const int* __restrict__ cols,
    const float* __restrict__ vals, const float* __restrict__ srcU,
    const float* __restrict__ srcI, float* __restrict__ dst,
    float scale, int nEdges, int nUsers)
{
    const int lane = threadIdx.x & 63;
    const int wavesPerBlock = blockDim.x >> 6;
    long wave = (long)blockIdx.x * wavesPerBlock + (threadIdx.x >> 6);
    const long nWaves = (long)gridDim.x * wavesPerBlock;
    for (long e = wave; e < nEdges; e += nWaves) {
        const int r = rows[e];
        const int c = cols[e];
        const float v = vals[e] * scale;
        const float* src;
        if (srcI != nullptr) {
            src = (c < nUsers) ? (srcU + (size_t)c * DIM)
                               : (srcI + (size_t)(c - nUsers) * DIM);
        } else {
            src = srcU + (size_t)c * DIM;
        }
        atomicAdd(dst + (size_t)r * DIM + lane, v * src[lane]);
    }
}

__global__ __launch_bounds__(256) void finalize_base(
    const float* __restrict__ userE, const float* __restrict__ itemE,
    const float* __restrict__ cur1, float* __restrict__ out, int nNodes, int nUsers)
{
    const long total4 = (long)nNodes * DIM / 4;
    const long user4  = (long)nUsers * DIM / 4;
    const float inv3 = 1.0f / 3.0f;
    for (long i = (long)blockIdx.x * blockDim.x + threadIdx.x; i < total4;
         i += (long)gridDim.x * blockDim.x) {
        float4 e = (i < user4) ? ((const float4*)userE)[i]
                               : ((const float4*)itemE)[i - user4];
        float4 c = ((const float4*)cur1)[i];
        float4 o;
        o.x = (e.x + c.x) * inv3; o.y = (e.y + c.y) * inv3;
        o.z = (e.z + c.z) * inv3; o.w = (e.w + c.w) * inv3;
        ((float4*)out)[i] = o;
    }
}

// ----------------------------------------------------------------

static inline size_t align256(size_t x) { return (x + 255) & ~(size_t)255; }

extern "C" void kernel_launch(void* const* d_in, const int* in_sizes, int n_in,
                              void* d_out, int out_size, void* d_ws, size_t ws_size,
                              hipStream_t stream)
{
    const int*   rows  = (const int*)d_in[0];
    const int*   cols  = (const int*)d_in[1];
    const float* vals  = (const float*)d_in[2];
    const float* userE = (const float*)d_in[3];
    const float* itemE = (const float*)d_in[4];
    float* out = (float*)d_out;

    const int nE     = in_sizes[0];
    const int nUsers = in_sizes[3] / DIM;
    const int nItems = in_sizes[4] / DIM;
    const int nNodes = nUsers + nItems;

    // workspace layout
    const size_t cur1Off   = 0;
    const size_t cur1B     = (size_t)nNodes * DIM * sizeof(float);
    const size_t cntOff    = align256(cur1Off + cur1B);
    const size_t cntB      = (size_t)nNodes * sizeof(int);
    const size_t rsOff     = align256(cntOff + cntB);
    const size_t rsB       = ((size_t)nNodes + 1) * sizeof(int);
    const size_t curOff    = align256(rsOff + rsB);
    const size_t curB      = (size_t)nNodes * sizeof(int);
    const size_t bsOff     = align256(curOff + curB);
    const size_t bsB       = 512 * sizeof(int);
    const size_t boOff     = align256(bsOff + bsB);
    const size_t boB       = 512 * sizeof(int);
    const size_t pairOff   = align256(boOff + boB);
    const size_t pairB     = (size_t)nE * sizeof(int2);
    const size_t required  = pairOff + pairB;

    char* ws = (char*)d_ws;
    float* cur1 = (float*)(ws + cur1Off);

    if (ws_size >= required) {
        int*  counts    = (int*)(ws + cntOff);
        int*  rowStart  = (int*)(ws + rsOff);
        int*  cursor    = (int*)(ws + curOff);
        int*  blockSums = (int*)(ws + bsOff);
        int*  blockOffs = (int*)(ws + boOff);
        int2* pairs     = (int2*)(ws + pairOff);

        const int nB = (nNodes + 1023) / 1024;   // 293 for 300K nodes

        hipMemsetAsync(counts, 0, cntB, stream);
        k_hist<<<dim3((nE + 255) / 256), dim3(256), 0, stream>>>(rows, counts, nE);
        k_scan1<<<dim3(nB), dim3(1024), 0, stream>>>(counts, rowStart, blockSums, nNodes);
        k_scan2<<<dim3(1), dim3(512), 0, stream>>>(blockSums, blockOffs, nB,
                                                   rowStart + nNodes, nE);
        k_scan3<<<dim3(nB), dim3(1024), 0, stream>>>(rowStart, blockOffs, nNodes);
        hipMemcpyAsync(cursor, rowStart, curB, hipMemcpyDeviceToDevice, stream);
        k_scatter<<<dim3((nE + 255) / 256), dim3(256), 0, stream>>>(rows, cols, vals,
                                                                    cursor, pairs, nE);

        const int rowsPerBlock = 4;              // 4 waves of 64
        dim3 sgrid((nNodes + rowsPerBlock - 1) / rowsPerBlock), sblk(256);
        k_spmm1<<<sgrid, sblk, 0, stream>>>(rowStart, pairs, userE, itemE, cur1,
                                            nNodes, nUsers);
        k_spmm2<<<sgrid, sblk, 0, stream>>>(rowStart, pairs, cur1, userE, itemE, out,
                                            nNodes, nUsers);
    } else {
        // fallback: atomic scatter path (round-1)
        hipMemsetAsync(cur1, 0, cur1B, stream);
        dim3 blk(256);
        spmm_scatter<<<dim3(4096), blk, 0, stream>>>(rows, cols, vals, userE, itemE,
                                                     cur1, 1.0f, nE, nUsers);
        finalize_base<<<dim3(2048), blk, 0, stream>>>(userE, itemE, cur1, out,
                                                      nNodes, nUsers);
        spmm_scatter<<<dim3(4096), blk, 0, stream>>>(rows, cols, vals, cur1, nullptr,
                                                     out, 1.0f / 3.0f, nE, nUsers);
    }
}